// Round 3
// baseline (24.230 us; speedup 1.0000x reference)
//
#include <hip/hip_runtime.h>

// Masked normalized cross-correlation, b=8, c=1, H=W=128, p=9.
// R2: no LDS at all. Mask read per-lane directly from global (each mask
// element is consumed by exactly one lane exactly once -> staging was a
// pure LDS-pipe round trip). x1/x2 (1 MB) are L2-resident -> direct global
// reads. Zero barriers, zero LDS -> entire 960-block grid co-resident in
// one dispatch round (R1 had 1.25 rounds + ~5us of LDS-pipe serialization).
// 2 lanes per patch (element halves 0..44 / 45..80); shuffle-combine;
// block-reduce; partials in d_ws; tiny finalize kernel.

#define BATCH 8
#define HH    128
#define WW    128
#define PP    9
#define HP    120
#define WP    120
#define NPATCH (HP * WP)        // 14400
#define PSQ   (PP * PP)         // 81
#define EPSF  1e-5f

__global__ __launch_bounds__(256) void ncc_kernel(const float* __restrict__ x1,
                                                  const float* __restrict__ x2,
                                                  const float* __restrict__ mask,
                                                  float* __restrict__ part)
{
    const int blk  = blockIdx.x;          // 0 .. 8*120-1
    const int b    = blk / HP;
    const int i    = blk - b * HP;        // patch row
    const int tid  = threadIdx.x;

    const int j = tid >> 1;               // patch column
    const int h = tid & 1;                // element-half selector

    float val = 0.0f;
    if (j < WP) {
        // h=0: elements 0..44 (rows 0..4); h=1: elements 45..80 (rows 5..8).
        // element e = 45*h + t; r = t/9 + 5*h; c = t%9  (45 = 5*9).
        const float* mrow = mask + ((size_t)b * NPATCH + (size_t)i * WP + j) * PSQ + h * 45;
        const float* x1b  = x1 + ((size_t)(b * HH + i + h * 5)) * WW + j;
        const float* x2b  = x2 + ((size_t)(b * HH + i + h * 5)) * WW + j;
        const int n = 45 - 9 * h;         // 45 or 36 live iterations

        float sa = 0.f, saa = 0.f, sb = 0.f, sbb = 0.f, sab = 0.f;
        #pragma unroll
        for (int t = 0; t < 45; ++t) {
            const int r = t / 9;          // compile-time per unrolled iter
            const int c = t - 9 * r;
            if (t < n) {
                float a  = x1b[r * WW + c];
                float m  = mrow[t];
                float bv = x2b[r * WW + c] * m;
                sa += a;
                saa = fmaf(a, a, saa);
                sb += bv;
                sbb = fmaf(bv, bv, sbb);
                sab = fmaf(a, bv, sab);
            }
        }
        // combine the two element-halves of this patch (partner lane = tid^1)
        sa  += __shfl_xor(sa, 1);
        saa += __shfl_xor(saa, 1);
        sb  += __shfl_xor(sb, 1);
        sbb += __shfl_xor(sbb, 1);
        sab += __shfl_xor(sab, 1);
        if (h == 0) {
            const float invN = 1.0f / 81.0f;
            float mua  = sa * invN;
            float mub  = sb * invN;
            float vara = saa * invN - mua * mua + EPSF;
            float varb = sbb * invN - mub * mub + EPSF;
            float cov  = sab - 81.0f * mua * mub;
            val = cov / sqrtf(vara * varb);
        }
    }

    // ---- block reduction -> one plain store per block ----
    __shared__ float wsum[4];
    #pragma unroll
    for (int off = 32; off > 0; off >>= 1)
        val += __shfl_down(val, off);
    const int wave = tid >> 6;
    if ((tid & 63) == 0) wsum[wave] = val;
    __syncthreads();
    if (tid == 0)
        part[blk] = wsum[0] + wsum[1] + wsum[2] + wsum[3];
}

__global__ __launch_bounds__(128) void finalize_kernel(const float* __restrict__ part,
                                                       float* __restrict__ out)
{
    const int b = blockIdx.x;       // 0..7
    const int t = threadIdx.x;      // 0..127
    float v = (t < HP) ? part[b * HP + t] : 0.0f;
    #pragma unroll
    for (int off = 32; off > 0; off >>= 1)
        v += __shfl_down(v, off);
    __shared__ float s[2];
    if ((t & 63) == 0) s[t >> 6] = v;
    __syncthreads();
    if (t == 0)
        out[b] = (s[0] + s[1]) * (1.0f / ((float)NPATCH * (float)PSQ));
}

extern "C" void kernel_launch(void* const* d_in, const int* in_sizes, int n_in,
                              void* d_out, int out_size, void* d_ws, size_t ws_size,
                              hipStream_t stream) {
    const float* x1   = (const float*)d_in[0];
    const float* x2   = (const float*)d_in[1];
    const float* mask = (const float*)d_in[2];
    float* out  = (float*)d_out;
    float* part = (float*)d_ws;     // 960 floats of scratch

    ncc_kernel<<<BATCH * HP, 256, 0, stream>>>(x1, x2, mask, part);
    finalize_kernel<<<BATCH, 128, 0, stream>>>(part, out);
}

// Round 4
// 17.565 us; speedup vs baseline: 1.3795x; 1.3795x over previous
//
#include <hip/hip_runtime.h>

// Masked normalized cross-correlation, b=8, c=1, H=W=128, p=9.
// R3: R2's no-LDS direct-global mask read regressed (scattered per-lane
// addresses -> TA request-rate bound). Back to LDS staging (R1's compute,
// verified), but: half-row blocks (60 patches, 128 threads, 24.6 KB LDS)
// -> 6 blocks/CU co-resident so staging of some blocks overlaps compute of
// others (R1 had 3 big lockstep blocks/CU + 1.25-round tail). x1/x2 also
// staged via global_load_lds using PER-LANE source addresses (LDS dest is
// lane-linear as required; global src may scatter) -> zero staging VALU.

#define BATCH 8
#define HH    128
#define WW    128
#define PP    9
#define HP    120
#define WP    120
#define NPATCH (HP * WP)        // 14400
#define PSQ   (PP * PP)         // 81
#define EPSF  1e-5f
#define CP    60                // patches per block (half patch-row)
#define XW    72                // padded x_lds row width (cols j0..j0+71)
#define NBLK  (BATCH * HP * 2)  // 1920

__device__ __forceinline__ void gload16(const void* g, void* lds) {
    __builtin_amdgcn_global_load_lds(
        (const __attribute__((address_space(1))) void*)g,
        (__attribute__((address_space(3))) void*)lds, 16, 0, 0);
}

__global__ __launch_bounds__(128) void ncc_kernel(const float* __restrict__ x1,
                                                  const float* __restrict__ x2,
                                                  const float* __restrict__ mask,
                                                  float* __restrict__ part)
{
    const int blk  = blockIdx.x;          // 0 .. 1919
    const int b    = blk / 240;
    const int rest = blk - b * 240;
    const int i    = rest >> 1;           // patch row
    const int j0   = (rest & 1) * CP;     // 0 or 60
    const int tid  = threadIdx.x;
    const int lane = tid & 63;

    __shared__ __align__(16) float m_lds[CP * PSQ];     // 4860 f = 19440 B
    __shared__ __align__(16) float x_lds[2][PP][XW];    // 1296 f =  5184 B
    __shared__ float wsum[2];

    // ---- stage mask chunk: 60 patches * 81 floats = 1215 float4 ----
    {
        const float4* msrc = reinterpret_cast<const float4*>(
            mask + ((size_t)b * NPATCH + (size_t)i * WP + j0) * PSQ);
        char* mdst = reinterpret_cast<char*>(m_lds);
        #pragma unroll
        for (int k = 0; k < 10; ++k) {
            int g = k * 128 + tid;                 // float4 index
            if (g < (CP * PSQ) / 4)                // 1215
                gload16(msrc + g, mdst + (size_t)(g - lane) * 16);
        }
    }
    // ---- stage x1/x2 rows i..i+8, cols j0..j0+71 (18 float4/row) ----
    {
        const float4* s1 = reinterpret_cast<const float4*>(
            x1 + ((size_t)(b * HH + i)) * WW + j0);
        const float4* s2 = reinterpret_cast<const float4*>(
            x2 + ((size_t)(b * HH + i)) * WW + j0);
        char* d1 = reinterpret_cast<char*>(&x_lds[0][0][0]);
        char* d2 = reinterpret_cast<char*>(&x_lds[1][0][0]);
        #pragma unroll
        for (int k = 0; k < 2; ++k) {
            int t = k * 128 + tid;                 // float4 index in [r][c4]
            if (t < (PP * XW) / 4) {               // 162
                int r  = t / (XW / 4);             // /18 (magic div)
                int c4 = t - r * (XW / 4);
                gload16(s1 + r * (WW / 4) + c4, d1 + (size_t)(t - lane) * 16);
                gload16(s2 + r * (WW / 4) + c4, d2 + (size_t)(t - lane) * 16);
            }
        }
    }
    __syncthreads();   // drains vmcnt(0)

    // ---- compute: 2 lanes per patch (rows 0..4 / rows 5..8) ----
    float val = 0.0f;
    const int j = tid >> 1;      // local patch column 0..59 (tid<120)
    const int h = tid & 1;       // half selector
    if (j < CP) {
        const int r0 = h ? 5 : 0;
        const int r1 = h ? 9 : 5;
        float sa = 0.f, saa = 0.f, sb = 0.f, sbb = 0.f, sab = 0.f;
        const float* mp = m_lds + j * PSQ + h * 45;
        for (int r = r0; r < r1; ++r) {
            const float* x1r = &x_lds[0][r][j];
            const float* x2r = &x_lds[1][r][j];
            #pragma unroll
            for (int cc = 0; cc < PP; ++cc) {
                float a  = x1r[cc];
                float bv = x2r[cc] * mp[cc];
                sa += a;
                saa = fmaf(a, a, saa);
                sb += bv;
                sbb = fmaf(bv, bv, sbb);
                sab = fmaf(a, bv, sab);
            }
            mp += PP;
        }
        sa  += __shfl_xor(sa, 1);
        saa += __shfl_xor(saa, 1);
        sb  += __shfl_xor(sb, 1);
        sbb += __shfl_xor(sbb, 1);
        sab += __shfl_xor(sab, 1);
        if (h == 0) {
            const float invN = 1.0f / 81.0f;
            float mua  = sa * invN;
            float mub  = sb * invN;
            float vara = saa * invN - mua * mua + EPSF;
            float varb = sbb * invN - mub * mub + EPSF;
            float cov  = sab - 81.0f * mua * mub;
            val = cov / sqrtf(vara * varb);
        }
    }

    // ---- block reduction (2 waves) -> one plain store per block ----
    #pragma unroll
    for (int off = 32; off > 0; off >>= 1)
        val += __shfl_down(val, off);
    if ((tid & 63) == 0) wsum[tid >> 6] = val;
    __syncthreads();
    if (tid == 0)
        part[blk] = wsum[0] + wsum[1];
}

__global__ __launch_bounds__(256) void finalize_kernel(const float* __restrict__ part,
                                                       float* __restrict__ out)
{
    const int b = blockIdx.x;       // 0..7
    const int t = threadIdx.x;      // 0..255
    float v = (t < 240) ? part[b * 240 + t] : 0.0f;
    #pragma unroll
    for (int off = 32; off > 0; off >>= 1)
        v += __shfl_down(v, off);
    __shared__ float s[4];
    if ((t & 63) == 0) s[t >> 6] = v;
    __syncthreads();
    if (t == 0)
        out[b] = (s[0] + s[1] + s[2] + s[3]) * (1.0f / ((float)NPATCH * (float)PSQ));
}

extern "C" void kernel_launch(void* const* d_in, const int* in_sizes, int n_in,
                              void* d_out, int out_size, void* d_ws, size_t ws_size,
                              hipStream_t stream) {
    const float* x1   = (const float*)d_in[0];
    const float* x2   = (const float*)d_in[1];
    const float* mask = (const float*)d_in[2];
    float* out  = (float*)d_out;
    float* part = (float*)d_ws;     // 1920 floats of scratch

    ncc_kernel<<<NBLK, 128, 0, stream>>>(x1, x2, mask, part);
    finalize_kernel<<<BATCH, 256, 0, stream>>>(part, out);
}